// Round 4
// baseline (267.305 us; speedup 1.0000x reference)
//
#include <hip/hip_runtime.h>
#include <hip/hip_bf16.h>
#include <hip/hip_fp16.h>
#include <math.h>

// Problem constants
constexpr int N_NODES = 50000;
constexpr int E_EDGES = 800000;
constexpr float NEG_SLOPE = 0.2f;
constexpr int CAP = 64;   // fixed CSR capacity/dst. deg ~ Poisson(16)+1; P(>63)~1e-17.
constexpr int G1_BLOCKS   = (N_NODES + 63) / 64;        // 782 gemm1-role blocks
constexpr int LINK_BLOCKS = (E_EDGES + 255) / 256;      // 3125 link-role blocks (1 edge/thr)

typedef _Float16 half8 __attribute__((ext_vector_type(8)));
typedef _Float16 half2v __attribute__((ext_vector_type(2)));
typedef float    floatx4 __attribute__((ext_vector_type(4)));

static inline int cdiv(long long a, int b) { return (int)((a + b - 1) / b); }

__device__ inline float leaky(float a) { return a > 0.f ? a : NEG_SLOPE * a; }
__device__ inline unsigned pack2h(float a, float b) {
    union { _Float16 h[2]; unsigned u; } p;
    p.h[0] = (_Float16)a; p.h[1] = (_Float16)b; return p.u;
}
__device__ inline float2 unp2h(unsigned u) {
    __half2 hh = *reinterpret_cast<__half2*>(&u);
    return __half22float2(hh);
}
__device__ inline float sel4(const float4& v, int h) {
    float a = (h & 2) ? v.z : v.x;
    float b = (h & 2) ? v.w : v.y;
    return (h & 1) ? b : a;
}

#if __has_builtin(__builtin_amdgcn_fdot2)
__device__ inline float dot2f(half2v a, half2v b, float c) {
    return __builtin_amdgcn_fdot2(a, b, c, false);
}
#else
__device__ inline float dot2f(half2v a, half2v b, float c) {
    return c + (float)a[0] * (float)b[0] + (float)a[1] * (float)b[1];
}
#endif

// ====== prep: zero deg + transpose W1/W2 to f16 [col][k] ======
// w1t[c*128+k] = W1[k][c]  (c<128, k<128);  w2t[c*128+k] = W2[k][c]  (c<40, k<128)
__global__ __launch_bounds__(256) void prep_kernel(const float* __restrict__ W1,
                                                   const float* __restrict__ W2,
                                                   int* __restrict__ deg,
                                                   _Float16* __restrict__ w1t,
                                                   _Float16* __restrict__ w2t) {
    int b = blockIdx.x, t = threadIdx.x;
    if (b < 196) {                          // zero deg
        int i = b * 256 + t;
        if (i < N_NODES) deg[i] = 0;
        return;
    }
    if (b < 196 + 64) {                     // W1 transpose: 16384 elems
        int idx = (b - 196) * 256 + t;
        int k = idx >> 7, c = idx & 127;    // read coalesced over c
        w1t[c * 128 + k] = (_Float16)W1[k * 128 + c];
        return;
    }
    {                                       // W2 transpose: 5120 elems (20 blocks)
        int idx = (b - 260) * 256 + t;
        int k = idx / 40, c = idx - k * 40;
        w2t[c * 128 + k] = (_Float16)W2[k * 40 + c];
    }
}

// ====== Fused: link (blocks < LINK_BLOCKS) ∥ GEMM1 (MFMA f16)+att1 (rest) ======
// R19: link-role blocks FIRST in the grid -- they're the long pole; dispatch order
// starts them before gemm-role blocks. Link = 1 edge/thread (R18 evidence: the
// atomic->scatter chain is latency-bound and lives on wave count).
__global__ __launch_bounds__(256, 8) void gemm1_link_kernel(const float* __restrict__ x,
                                                            const _Float16* __restrict__ w1t,
                                                            const float* __restrict__ as1,
                                                            const float* __restrict__ ad1,
                                                            unsigned short* __restrict__ h1h,
                                                            float* __restrict__ als,
                                                            float* __restrict__ ald,
                                                            const int* __restrict__ ei,
                                                            int* __restrict__ deg,
                                                            unsigned short* __restrict__ csr16) {
    __shared__ _Float16 xS[64 * 136];    // 17.4 KB (X f16; reused as C buffer)
    __shared__ float asld[128], adld[128];
    int t = threadIdx.x;

    if (blockIdx.x < LINK_BLOCKS) {      // ---- link role: 1 edge per thread ----
        int e = blockIdx.x * 256 + t;
        if (e < E_EDGES) {
            int s = ei[e], d = ei[E_EDGES + e];
            int slot = atomicAdd(&deg[d], 1) + 1;   // slot 0 reserved for self-loop
            if (slot < CAP) csr16[d * CAP + slot] = (unsigned short)s;
        }
        return;
    }

    // ---- gemm1 role ----
    int row0 = (blockIdx.x - LINK_BLOCKS) * 64;
    if (t < 128) { asld[t] = as1[t]; adld[t] = ad1[t]; }
    // stage X (f32 -> f16), full 128-K
    #pragma unroll
    for (int i = 0; i < 8; ++i) {
        int fi = i * 256 + t;            // 0..2047
        int r = fi >> 5, c4 = (fi & 31) * 4;
        int gr = row0 + r;
        float4 v = make_float4(0.f, 0.f, 0.f, 0.f);
        if (gr < N_NODES) v = *(const float4*)&x[(size_t)gr * 128 + c4];
        union { _Float16 h[4]; uint2 u; } pk;
        pk.h[0] = (_Float16)v.x; pk.h[1] = (_Float16)v.y;
        pk.h[2] = (_Float16)v.z; pk.h[3] = (_Float16)v.w;
        *(uint2*)&xS[r * 136 + c4] = pk.u;
    }
    __syncthreads();

    int w = t >> 6, lane = t & 63, quad = lane >> 4, l16 = lane & 15;
    floatx4 z = {0.f, 0.f, 0.f, 0.f};
    floatx4 c[4][2];
    #pragma unroll
    for (int rt = 0; rt < 4; ++rt) { c[rt][0] = z; c[rt][1] = z; }

    const _Float16* wt0 = w1t + (size_t)(w * 32 + l16) * 128;   // column (w*32+l16)
    const _Float16* wt1 = wt0 + 16 * 128;                       // column +16
    #pragma unroll
    for (int ks = 0; ks < 4; ++ks) {
        int kg = ks * 32 + quad * 8;
        half8 b0 = *(const half8*)&wt0[kg];
        half8 b1 = *(const half8*)&wt1[kg];
        #pragma unroll
        for (int rt = 0; rt < 4; ++rt) {
            half8 a = *(const half8*)&xS[(rt * 16 + l16) * 136 + kg];
            c[rt][0] = __builtin_amdgcn_mfma_f32_16x16x32_f16(a, b0, c[rt][0], 0, 0, 0);
            c[rt][1] = __builtin_amdgcn_mfma_f32_16x16x32_f16(a, b1, c[rt][1], 0, 0, 0);
        }
    }
    __syncthreads();
    // transpose C into xS region as f16 (64 rows x stride 136; 8704 slots exactly)
    _Float16* cbuf = xS;
    #pragma unroll
    for (int rt = 0; rt < 4; ++rt)
        #pragma unroll
        for (int ctl = 0; ctl < 2; ++ctl)
            #pragma unroll
            for (int reg = 0; reg < 4; ++reg)
                cbuf[(rt * 16 + quad * 4 + reg) * 136 + (w * 32 + ctl * 16 + l16)]
                    = (_Float16)c[rt][ctl][reg];
    __syncthreads();
    // epilogue: thread t -> (row r, head hq); store h1 row segment + logits + self-loop
    int r = t >> 2, hq = t & 3;
    int n = row0 + r;
    if (n < N_NODES) {
        if (hq == 0) csr16[n * CAP] = (unsigned short)n;   // self-loop slot 0
        float ps = 0.f, pd = 0.f;
        #pragma unroll
        for (int i = 0; i < 4; ++i) {
            uint4 uv = *(uint4*)&cbuf[r * 136 + hq * 32 + i * 8];
            *(uint4*)&h1h[(size_t)n * 128 + hq * 32 + i * 8] = uv;
            union { uint4 u; _Float16 h[8]; } cv; cv.u = uv;
            #pragma unroll
            for (int k = 0; k < 8; ++k) {
                float v = (float)cv.h[k];
                ps += v * asld[hq * 32 + i * 8 + k];
                pd += v * adld[hq * 32 + i * 8 + k];
            }
        }
        als[n * 4 + hq] = ps;
        ald[n * 4 + hq] = pd;
    }
}

// ===== layer1 fused single-pass softmax-aggregate + FUSED GEMM2 + att2 =====
// R19: gemm2 absorbed into the epilogue. Each wave holds its dst's finished out1
// row (f16 in LDS, 256B); lanes 0..39 each compute one h2 channel via 64
// v_dot2_f32_f16 against w2t rows (10KB, L1-resident), then shuffle-reduce the
// att2 logits. Kills the out1h 25.6MB round-trip + the whole gemm2 dispatch.
__global__ __launch_bounds__(256) void agg1_kernel(const int* __restrict__ deg_,
                                                   const unsigned short* __restrict__ csr16,
                                                   const float* __restrict__ als,
                                                   const float4* __restrict__ ald4,
                                                   const unsigned short* __restrict__ h1h,
                                                   const float* __restrict__ b1,
                                                   const _Float16* __restrict__ w2t,
                                                   const float* __restrict__ as2g,
                                                   const float* __restrict__ ad2g,
                                                   unsigned short* __restrict__ h2h,
                                                   float* __restrict__ als2,
                                                   float* __restrict__ ald2) {
    __shared__ _Float16 rowS[4][128];         // per-wave out1 row (1KB)
    int wv   = threadIdx.x >> 6;
    int lane = threadIdx.x & 63;
    int half = lane >> 5;                     // 0: even edges, 1: odd edges
    int l    = lane & 31;                     // channel quad: channels 4l..4l+3
    int myhead = l >> 3;                      // 32 channels per head
    int we   = lane & 15;                     // weight-role: edge offset
    int wh   = lane >> 4;                     // weight-role: head
    int d    = blockIdx.x * 4 + wv;           // grid exactly covers N
    int dg   = min(deg_[d] + 1, CAP);         // +1: self-loop at slot 0
    int base = d * CAP;
    float4 aldd = ald4[d];
    float d_hw = sel4(aldd, wh);              // weight-role ald component (loop-invariant)

    float sm = 0.f;
    float acc[4] = {0.f, 0.f, 0.f, 0.f};
    int sfirst = (int)csr16[base];            // self-loop: always valid
    #pragma unroll 2
    for (int j = 0; j < dg; j += 16) {
        // ---- weight phase: one (edge,head) per lane ----
        int s_w = (int)csr16[base + j + we];  // lanes share a 32B segment (broadcast)
        float av = als[s_w * 4 + wh];         // L2-resident 800KB table gather
        float wgt = (j + we < dg) ? __expf(leaky(av + d_hw)) : 0.f;
        // ---- index phase for my half's 8 edges ----
        uint4 blkA = *(const uint4*)&csr16[base + j];       // 16B aligned
        uint4 blkB = *(const uint4*)&csr16[base + j + 8];
        unsigned bw[8] = { blkA.x, blkA.y, blkA.z, blkA.w,
                           blkB.x, blkB.y, blkB.z, blkB.w };
        int ss[8];
        #pragma unroll
        for (int p = 0; p < 8; ++p) {
            unsigned b = __builtin_amdgcn_readfirstlane(bw[p]);
            int e0 = (int)(b & 0xffff), e1 = (int)(b >> 16);
            int mys = half ? e1 : e0;
            if (j + 2 * p + half >= dg) mys = sfirst;
            ss[p] = mys;
        }
        uint2 hv[8];
        #pragma unroll
        for (int p = 0; p < 8; ++p)
            hv[p] = *(const uint2*)(h1h + ((size_t)ss[p] << 7) + 4 * l);
        // ---- fetch my 8 weights via bpermute ----
        float ww[8];
        #pragma unroll
        for (int p = 0; p < 8; ++p) {
            ww[p] = __shfl(wgt, 16 * myhead + 2 * p + half);
            sm += ww[p];
        }
        half2v hacc0 = { (_Float16)0.f, (_Float16)0.f };
        half2v hacc1 = { (_Float16)0.f, (_Float16)0.f };
        #pragma unroll
        for (int p = 0; p < 8; ++p) {
            half2v v0 = *reinterpret_cast<half2v*>(&hv[p].x);
            half2v v1 = *reinterpret_cast<half2v*>(&hv[p].y);
            _Float16 hw = (_Float16)ww[p];
            half2v hwv = { hw, hw };
            hacc0 += v0 * hwv;                // v_pk_fma_f16
            hacc1 += v1 * hwv;
        }
        acc[0] += (float)hacc0[0]; acc[1] += (float)hacc0[1];
        acc[2] += (float)hacc1[0]; acc[3] += (float)hacc1[1];
    }
    // cross-half reduce (lanes l and l+32 hold same channels, disjoint edges)
    sm += __shfl_xor(sm, 32);
    #pragma unroll
    for (int k = 0; k < 4; ++k) acc[k] += __shfl_xor(acc[k], 32);
    if (half == 0) {
        float inv = 1.f / (sm + 1e-16f);
        float v[4];
        #pragma unroll
        for (int k = 0; k < 4; ++k) {
            v[k] = acc[k] * inv + b1[4 * l + k];
            v[k] = v[k] > 0.f ? v[k] : __expf(v[k]) - 1.f;
        }
        uint2 o;
        o.x = pack2h(v[0], v[1]);
        o.y = pack2h(v[2], v[3]);
        *(uint2*)&rowS[wv][4 * l] = o;        // out1 row -> LDS (was global out1h)
    }
    // ---- fused GEMM2: lane c (<40) computes h2[d][c] = out1[d] . w2t[c] ----
    float h2c = 0.f;
    if (lane < 40) {
        const half8* wr = (const half8*)(w2t + (size_t)lane * 128);
        const half8* xr = (const half8*)rowS[wv];
        #pragma unroll
        for (int kk = 0; kk < 16; ++kk) {
            half8 a = xr[kk], b = wr[kk];
            #pragma unroll
            for (int q = 0; q < 4; ++q) {
                half2v a2 = { a[2 * q], a[2 * q + 1] };
                half2v b2 = { b[2 * q], b[2 * q + 1] };
                h2c = dot2f(a2, b2, h2c);
            }
        }
    }
    // att2 logits: ps/pd = sum_c h2[c]*as2[c] / ad2[c]  (64-lane xor reduce)
    float ps = (lane < 40) ? h2c * as2g[lane] : 0.f;
    float pd = (lane < 40) ? h2c * ad2g[lane] : 0.f;
    #pragma unroll
    for (int off = 1; off < 64; off <<= 1) {
        ps += __shfl_xor(ps, off);
        pd += __shfl_xor(pd, off);
    }
    if (lane == 0) { als2[d] = ps; ald2[d] = pd; }
    if (lane < 40) {
        union { _Float16 h; unsigned short u; } cv; cv.h = (_Float16)h2c;
        h2h[(size_t)d * 40 + lane] = cv.u;
    }
}

// ===== layer2 fused single-pass, masked 12-blocks (4 per slot, no serial tail) =====
__global__ __launch_bounds__(256) void agg2_kernel(const int* __restrict__ deg_,
                                                   const unsigned short* __restrict__ csr16,
                                                   const float* __restrict__ als,
                                                   const float* __restrict__ ald,
                                                   const unsigned short* __restrict__ h2h,
                                                   const float* __restrict__ b2,
                                                   float* __restrict__ out) {
    int wv   = threadIdx.x >> 6;
    int lane = threadIdx.x & 63;
    int d    = blockIdx.x * 4 + wv;
    int dg   = min(deg_[d] + 1, CAP);      // +1: self-loop at slot 0
    int base = d * CAP;
    float aldd = ald[d];

    int slot = lane / 20;              // 0..2 active, 3 idle
    int idx  = lane - slot * 20;       // channel pair 0..19
    int sfirst = (int)csr16[base];
    float sm = 0.f, acc0 = 0.f, acc1 = 0.f;
    if (lane < 60) {
        for (int jb = 0; jb < dg; jb += 12) {
            int ss[4]; unsigned hv[4]; float ww[4];
            #pragma unroll
            for (int i = 0; i < 4; ++i) {
                int jj = jb + slot + 3 * i;
                ss[i] = (jj < dg) ? (int)csr16[base + jj] : sfirst;
            }
            #pragma unroll
            for (int i = 0; i < 4; ++i)
                hv[i] = *(const unsigned*)(h2h + (size_t)ss[i] * 40 + 2 * idx);
            #pragma unroll
            for (int i = 0; i < 4; ++i) {
                int jj = jb + slot + 3 * i;
                float w = __expf(leaky(als[ss[i]] + aldd));
                ww[i] = (jj < dg) ? w : 0.f;
            }
            #pragma unroll
            for (int i = 0; i < 4; ++i) {
                float2 f = unp2h(hv[i]);
                acc0 += f.x * ww[i]; acc1 += f.y * ww[i]; sm += ww[i];
            }
        }
    }
    // reduce sm/acc across the 3 slots: lanes idx, idx+20, idx+40
    float s1 = __shfl(sm,   idx + 20), s2 = __shfl(sm,   idx + 40);
    float t0 = __shfl(acc0, idx + 20), t1 = __shfl(acc0, idx + 40);
    float u0 = __shfl(acc1, idx + 20), u1 = __shfl(acc1, idx + 40);
    sm += s1 + s2; acc0 += t0 + t1; acc1 += u0 + u1;
    if (lane < 20) {
        float inv = 1.f / (sm + 1e-16f);
        float2 o = make_float2(acc0 * inv + b2[2 * lane], acc1 * inv + b2[2 * lane + 1]);
        *(float2*)&out[(size_t)d * 40 + 2 * lane] = o;
    }
}

// ================= workspace layout (float-sized slots) =================
constexpr size_t OFF_H1H    = 0;          // h1 f16 (3.2M slots)
constexpr size_t OFF_H2H    = 3200000;    // h2 f16 [N,40] = 1M slots (old out1 region)
constexpr size_t OFF_ALS1   = 6400000;    // 200,000
constexpr size_t OFF_ALD1   = 6600000;    // 200,000
constexpr size_t OFF_W1T    = 6800000;    // w1t f16 [128][128] = 8192 float slots
constexpr size_t OFF_W2T    = 6808192;    // w2t f16 [40][128]  = 2560 float slots
constexpr size_t OFF_DEG    = 6860000;    // 50,000 ints
constexpr size_t OFF_CSRF   = 6920000;    // 50,000*64 u16 = 1.6M float slots
constexpr size_t OFF_ALS2   = 8520000;    // 50,000 (own region: live with als1 in agg1)
constexpr size_t OFF_ALD2   = 8570000;    // 50,000
constexpr size_t WS_FLOATS  = 10120000;   // 40.5 MB

extern "C" void kernel_launch(void* const* d_in, const int* in_sizes, int n_in,
                              void* d_out, int out_size, void* d_ws, size_t ws_size,
                              hipStream_t stream) {
    const float* x   = (const float*)d_in[0];
    const int*   ei  = (const int*)  d_in[1];
    const float* W1  = (const float*)d_in[2];
    const float* as1 = (const float*)d_in[3];
    const float* ad1 = (const float*)d_in[4];
    const float* b1  = (const float*)d_in[5];
    const float* W2  = (const float*)d_in[6];
    const float* as2 = (const float*)d_in[7];
    const float* ad2 = (const float*)d_in[8];
    const float* b2  = (const float*)d_in[9];
    float* out = (float*)d_out;

    if (ws_size < WS_FLOATS * sizeof(float)) return;

    float* ws = (float*)d_ws;
    unsigned short* h1h   = (unsigned short*)(ws + OFF_H1H);
    unsigned short* h2h   = (unsigned short*)(ws + OFF_H2H);
    float* als1    = ws + OFF_ALS1;
    float* ald1    = ws + OFF_ALD1;
    float* als2    = ws + OFF_ALS2;
    float* ald2    = ws + OFF_ALD2;
    _Float16* w1t  = (_Float16*)(ws + OFF_W1T);
    _Float16* w2t  = (_Float16*)(ws + OFF_W2T);
    int*   deg     = (int*)(ws + OFF_DEG);
    unsigned short* csr16 = (unsigned short*)(ws + OFF_CSRF);

    // ---- prep (deg=0 + W transposes), then fused [link->CSR || gemm1] ----
    prep_kernel<<<280, 256, 0, stream>>>(W1, W2, deg, w1t, w2t);
    gemm1_link_kernel<<<G1_BLOCKS + LINK_BLOCKS, 256, 0, stream>>>(
        x, w1t, as1, ad1, h1h, als1, ald1, ei, deg, csr16);

    // ---- layer 1 aggregate + fused GEMM2 + att2 logits ----
    agg1_kernel<<<N_NODES / 4, 256, 0, stream>>>(deg, csr16, als1,
                                                 (const float4*)ald1,
                                                 h1h, b1, w2t, as2, ad2,
                                                 h2h, als2, ald2);

    // ---- layer 2 aggregate ----
    agg2_kernel<<<N_NODES / 4, 256, 0, stream>>>(deg, csr16, als2, ald2, h2h, b2, out);
}

// Round 5
// 224.733 us; speedup vs baseline: 1.1894x; 1.1894x over previous
//
#include <hip/hip_runtime.h>
#include <hip/hip_bf16.h>
#include <hip/hip_fp16.h>
#include <math.h>

// Problem constants
constexpr int N_NODES = 50000;
constexpr int E_EDGES = 800000;
constexpr float NEG_SLOPE = 0.2f;
constexpr int CAP = 64;   // fixed CSR capacity/dst. deg ~ Poisson(16)+1; P(>63)~1e-17.
constexpr int G1_BLOCKS   = (N_NODES + 63) / 64;        // 782 gemm1-role blocks
constexpr int LINK_BLOCKS = (E_EDGES + 255) / 256;      // 3125 link-role blocks (1 edge/thr)

typedef _Float16 half8 __attribute__((ext_vector_type(8)));
typedef _Float16 half2v __attribute__((ext_vector_type(2)));
typedef float    floatx4 __attribute__((ext_vector_type(4)));

static inline int cdiv(long long a, int b) { return (int)((a + b - 1) / b); }

__device__ inline float leaky(float a) { return a > 0.f ? a : NEG_SLOPE * a; }
__device__ inline unsigned pack2h(float a, float b) {
    union { _Float16 h[2]; unsigned u; } p;
    p.h[0] = (_Float16)a; p.h[1] = (_Float16)b; return p.u;
}
__device__ inline float2 unp2h(unsigned u) {
    __half2 hh = *reinterpret_cast<__half2*>(&u);
    return __half22float2(hh);
}
__device__ inline float sel4(const float4& v, int h) {
    float a = (h & 2) ? v.z : v.x;
    float b = (h & 2) ? v.w : v.y;
    return (h & 1) ? b : a;
}

// ====== prep: zero deg + transpose W1/W2 to f16 [col][k] ======
// w1t[c*128+k] = W1[k][c]  (c<128, k<128);  w2t[c*128+k] = W2[k][c]  (c<40, k<128)
__global__ __launch_bounds__(256) void prep_kernel(const float* __restrict__ W1,
                                                   const float* __restrict__ W2,
                                                   int* __restrict__ deg,
                                                   _Float16* __restrict__ w1t,
                                                   _Float16* __restrict__ w2t) {
    int b = blockIdx.x, t = threadIdx.x;
    if (b < 196) {                          // zero deg
        int i = b * 256 + t;
        if (i < N_NODES) deg[i] = 0;
        return;
    }
    if (b < 196 + 64) {                     // W1 transpose: 16384 elems
        int idx = (b - 196) * 256 + t;
        int k = idx >> 7, c = idx & 127;    // read coalesced over c
        w1t[c * 128 + k] = (_Float16)W1[k * 128 + c];
        return;
    }
    {                                       // W2 transpose: 5120 elems (20 blocks)
        int idx = (b - 260) * 256 + t;
        int k = idx / 40, c = idx - k * 40;
        w2t[c * 128 + k] = (_Float16)W2[k * 40 + c];
    }
}

// ====== Fused: link (blocks < LINK_BLOCKS) ∥ GEMM1 (MFMA f16)+att1 (rest) ======
// R20: measured across R15-R18, the gemm role is FASTEST with B staged in LDS
// (R15: 47.5us @ 36.9KB/26-33% occ) vs global B-loads (R16/R18: 52-58us @ 60% occ)
// -- higher occupancy ADDED link-wave L2-atomic interference and lost the
// lgkmcnt-scheduled LDS feed. Restore R15's K-chunked W^T LDS staging, sourcing
// from pre-transposed f16 w1t (plain uint4 copies, no per-block pack VALU).
// Link role: 1 edge/thread, direct-slot CSR, blocks first in the grid.
__global__ __launch_bounds__(256) void gemm1_link_kernel(const float* __restrict__ x,
                                                         const _Float16* __restrict__ w1t,
                                                         const float* __restrict__ as1,
                                                         const float* __restrict__ ad1,
                                                         unsigned short* __restrict__ h1h,
                                                         float* __restrict__ als,
                                                         float* __restrict__ ald,
                                                         const int* __restrict__ ei,
                                                         int* __restrict__ deg,
                                                         unsigned short* __restrict__ csr16) {
    __shared__ _Float16 xS[64 * 136];    // 17.4 KB (X f16)
    __shared__ _Float16 wtS[128 * 72];   // 18.4 KB (W^T 64-K chunk; reused as C buffer)
    __shared__ float asld[128], adld[128];
    int t = threadIdx.x;

    if (blockIdx.x < LINK_BLOCKS) {      // ---- link role: 1 edge per thread ----
        int e = blockIdx.x * 256 + t;
        if (e < E_EDGES) {
            int s = ei[e], d = ei[E_EDGES + e];
            int slot = atomicAdd(&deg[d], 1) + 1;   // slot 0 reserved for self-loop
            if (slot < CAP) csr16[d * CAP + slot] = (unsigned short)s;
        }
        return;
    }

    // ---- gemm1 role ----
    int row0 = (blockIdx.x - LINK_BLOCKS) * 64;
    if (t < 128) { asld[t] = as1[t]; adld[t] = ad1[t]; }
    // stage X (f32 -> f16), full 128-K
    #pragma unroll
    for (int i = 0; i < 8; ++i) {
        int fi = i * 256 + t;            // 0..2047
        int r = fi >> 5, c4 = (fi & 31) * 4;
        int gr = row0 + r;
        float4 v = make_float4(0.f, 0.f, 0.f, 0.f);
        if (gr < N_NODES) v = *(const float4*)&x[(size_t)gr * 128 + c4];
        union { _Float16 h[4]; uint2 u; } pk;
        pk.h[0] = (_Float16)v.x; pk.h[1] = (_Float16)v.y;
        pk.h[2] = (_Float16)v.z; pk.h[3] = (_Float16)v.w;
        *(uint2*)&xS[r * 136 + c4] = pk.u;
    }

    int w = t >> 6, lane = t & 63, quad = lane >> 4, l16 = lane & 15;
    floatx4 z = {0.f, 0.f, 0.f, 0.f};
    floatx4 c[4][2];
    #pragma unroll
    for (int rt = 0; rt < 4; ++rt) { c[rt][0] = z; c[rt][1] = z; }

    #pragma unroll
    for (int kc = 0; kc < 2; ++kc) {
        __syncthreads();                 // X staged / previous chunk consumed
        // stage W^T chunk (k rows kc*64..+63) from w1t [col][k] f16: 1024 uint4 tasks
        #pragma unroll
        for (int i = 0; i < 4; ++i) {
            int fi = i * 256 + t;        // 0..1023
            int col = fi >> 3, k8 = (fi & 7) * 8;
            *(uint4*)&wtS[col * 72 + k8] = *(const uint4*)&w1t[col * 128 + kc * 64 + k8];
        }
        __syncthreads();
        #pragma unroll
        for (int ks2 = 0; ks2 < 2; ++ks2) {
            int ko = ks2 * 32 + quad * 8;           // within chunk
            half8 b0 = *(const half8*)&wtS[(w * 32 + l16) * 72 + ko];
            half8 b1 = *(const half8*)&wtS[(w * 32 + 16 + l16) * 72 + ko];
            #pragma unroll
            for (int rt = 0; rt < 4; ++rt) {
                half8 a = *(const half8*)&xS[(rt * 16 + l16) * 136 + kc * 64 + ko];
                c[rt][0] = __builtin_amdgcn_mfma_f32_16x16x32_f16(a, b0, c[rt][0], 0, 0, 0);
                c[rt][1] = __builtin_amdgcn_mfma_f32_16x16x32_f16(a, b1, c[rt][1], 0, 0, 0);
            }
        }
    }
    __syncthreads();
    // transpose C into wtS region as f16 (64 rows x stride 136; 8704 <= 9216 slots)
    _Float16* cbuf = wtS;
    #pragma unroll
    for (int rt = 0; rt < 4; ++rt)
        #pragma unroll
        for (int ctl = 0; ctl < 2; ++ctl)
            #pragma unroll
            for (int reg = 0; reg < 4; ++reg)
                cbuf[(rt * 16 + quad * 4 + reg) * 136 + (w * 32 + ctl * 16 + l16)]
                    = (_Float16)c[rt][ctl][reg];
    __syncthreads();
    // epilogue: thread t -> (row r, head hq); store h1 row segment + logits + self-loop
    int r = t >> 2, hq = t & 3;
    int n = row0 + r;
    if (n < N_NODES) {
        if (hq == 0) csr16[n * CAP] = (unsigned short)n;   // self-loop slot 0
        float ps = 0.f, pd = 0.f;
        #pragma unroll
        for (int i = 0; i < 4; ++i) {
            uint4 uv = *(uint4*)&cbuf[r * 136 + hq * 32 + i * 8];
            *(uint4*)&h1h[(size_t)n * 128 + hq * 32 + i * 8] = uv;
            union { uint4 u; _Float16 h[8]; } cv; cv.u = uv;
            #pragma unroll
            for (int k = 0; k < 8; ++k) {
                float v = (float)cv.h[k];
                ps += v * asld[hq * 32 + i * 8 + k];
                pd += v * adld[hq * 32 + i * 8 + k];
            }
        }
        als[n * 4 + hq] = ps;
        ald[n * 4 + hq] = pd;
    }
}

// ===== layer1 fused single-pass softmax-aggregate =====
// Weights: lane (we=lane&15, wh=lane>>4) computes exp for (edge we, head wh) -- ONE
// exp issue covers all 64 (edge,head) pairs of a 16-edge block.
// Gathers: split-wave (lanes 0-31 even edges / 32-63 odd), uint2 channel-quad per lane.
// unroll 2 on the j-loop doubles independent gather chains in flight.
__global__ __launch_bounds__(256) void agg1_kernel(const int* __restrict__ deg_,
                                                   const unsigned short* __restrict__ csr16,
                                                   const float* __restrict__ als,
                                                   const float4* __restrict__ ald4,
                                                   const unsigned short* __restrict__ h1h,
                                                   const float* __restrict__ b1,
                                                   unsigned short* __restrict__ out1h) {
    int wv   = threadIdx.x >> 6;
    int lane = threadIdx.x & 63;
    int half = lane >> 5;                     // 0: even edges, 1: odd edges
    int l    = lane & 31;                     // channel quad: channels 4l..4l+3
    int myhead = l >> 3;                      // 32 channels per head
    int we   = lane & 15;                     // weight-role: edge offset
    int wh   = lane >> 4;                     // weight-role: head
    int d    = blockIdx.x * 4 + wv;           // grid exactly covers N
    int dg   = min(deg_[d] + 1, CAP);         // +1: self-loop at slot 0
    int base = d * CAP;
    float4 aldd = ald4[d];
    float d_hw = sel4(aldd, wh);              // weight-role ald component (loop-invariant)

    float sm = 0.f;
    float acc[4] = {0.f, 0.f, 0.f, 0.f};
    int sfirst = (int)csr16[base];            // self-loop: always valid
    #pragma unroll 2
    for (int j = 0; j < dg; j += 16) {
        // ---- weight phase: one (edge,head) per lane ----
        int s_w = (int)csr16[base + j + we];  // lanes share a 32B segment (broadcast)
        float av = als[s_w * 4 + wh];         // L2-resident 800KB table gather
        float wgt = (j + we < dg) ? __expf(leaky(av + d_hw)) : 0.f;
        // ---- index phase for my half's 8 edges ----
        uint4 blkA = *(const uint4*)&csr16[base + j];       // 16B aligned
        uint4 blkB = *(const uint4*)&csr16[base + j + 8];
        unsigned bw[8] = { blkA.x, blkA.y, blkA.z, blkA.w,
                           blkB.x, blkB.y, blkB.z, blkB.w };
        int ss[8];
        #pragma unroll
        for (int p = 0; p < 8; ++p) {
            unsigned b = __builtin_amdgcn_readfirstlane(bw[p]);
            int e0 = (int)(b & 0xffff), e1 = (int)(b >> 16);
            int mys = half ? e1 : e0;
            if (j + 2 * p + half >= dg) mys = sfirst;
            ss[p] = mys;
        }
        uint2 hv[8];
        #pragma unroll
        for (int p = 0; p < 8; ++p)
            hv[p] = *(const uint2*)(h1h + ((size_t)ss[p] << 7) + 4 * l);
        // ---- fetch my 8 weights via bpermute ----
        float ww[8];
        #pragma unroll
        for (int p = 0; p < 8; ++p) {
            ww[p] = __shfl(wgt, 16 * myhead + 2 * p + half);
            sm += ww[p];
        }
        half2v hacc0 = { (_Float16)0.f, (_Float16)0.f };
        half2v hacc1 = { (_Float16)0.f, (_Float16)0.f };
        #pragma unroll
        for (int p = 0; p < 8; ++p) {
            half2v v0 = *reinterpret_cast<half2v*>(&hv[p].x);
            half2v v1 = *reinterpret_cast<half2v*>(&hv[p].y);
            _Float16 hw = (_Float16)ww[p];
            half2v hwv = { hw, hw };
            hacc0 += v0 * hwv;                // v_pk_fma_f16
            hacc1 += v1 * hwv;
        }
        acc[0] += (float)hacc0[0]; acc[1] += (float)hacc0[1];
        acc[2] += (float)hacc1[0]; acc[3] += (float)hacc1[1];
    }
    // cross-half reduce (lanes l and l+32 hold same channels, disjoint edges)
    sm += __shfl_xor(sm, 32);
    #pragma unroll
    for (int k = 0; k < 4; ++k) acc[k] += __shfl_xor(acc[k], 32);
    if (half == 0) {
        float inv = 1.f / (sm + 1e-16f);
        float v[4];
        #pragma unroll
        for (int k = 0; k < 4; ++k) {
            v[k] = acc[k] * inv + b1[4 * l + k];
            v[k] = v[k] > 0.f ? v[k] : __expf(v[k]) - 1.f;
        }
        uint2 o;
        o.x = pack2h(v[0], v[1]);
        o.y = pack2h(v[2], v[3]);
        *(uint2*)&out1h[(size_t)d * 128 + 4 * l] = o;
    }
}

// ===== GEMM2 (MFMA f16) + fused att2: h2h[N,40] f16, als2/ald2[N] =====
// B-fragments are half8 loads from pre-transposed w2t [40][128] (10KB).
__global__ __launch_bounds__(256, 8) void gemm2_kernel(const unsigned short* __restrict__ out1h,
                                                       const _Float16* __restrict__ w2t,
                                                       const float* __restrict__ as2,
                                                       const float* __restrict__ ad2,
                                                       unsigned short* __restrict__ h2h,
                                                       float* __restrict__ als,
                                                       float* __restrict__ ald) {
    __shared__ _Float16 aS[64 * 136];    // staging + C transpose
    __shared__ float asld[40], adld[40];
    int t = threadIdx.x;
    int row0 = blockIdx.x * 64;
    if (t < 40) { asld[t] = as2[t]; adld[t] = ad2[t]; }
    // stage A (f16 copy)
    #pragma unroll
    for (int i = 0; i < 4; ++i) {
        int fi = i * 256 + t;             // 0..1023
        int r = fi >> 4, s8 = (fi & 15) * 8;
        int gr = row0 + r;
        uint4 v = make_uint4(0u, 0u, 0u, 0u);
        if (gr < N_NODES) v = *(const uint4*)&out1h[(size_t)gr * 128 + s8];
        *(uint4*)&aS[r * 136 + s8] = v;
    }
    __syncthreads();

    int w = t >> 6, lane = t & 63, quad = lane >> 4, l16 = lane & 15;
    floatx4 z = {0.f, 0.f, 0.f, 0.f};
    floatx4 c0 = z, c1 = z, c2 = z;
    int n2 = (l16 < 8) ? 32 + l16 : 39;    // clamp: cols 40..47 feed discarded output
    const _Float16* wb0 = w2t + (size_t)l16 * 128;
    const _Float16* wb1 = w2t + (size_t)(16 + l16) * 128;
    const _Float16* wb2 = w2t + (size_t)n2 * 128;
    #pragma unroll
    for (int ks = 0; ks < 4; ++ks) {
        int kg = ks * 32 + quad * 8;
        half8 b0 = *(const half8*)&wb0[kg];
        half8 b1 = *(const half8*)&wb1[kg];
        half8 b2 = *(const half8*)&wb2[kg];
        half8 a  = *(const half8*)&aS[(w * 16 + l16) * 136 + kg];
        c0 = __builtin_amdgcn_mfma_f32_16x16x32_f16(a, b0, c0, 0, 0, 0);
        c1 = __builtin_amdgcn_mfma_f32_16x16x32_f16(a, b1, c1, 0, 0, 0);
        c2 = __builtin_amdgcn_mfma_f32_16x16x32_f16(a, b2, c2, 0, 0, 0);
    }
    __syncthreads();
    #pragma unroll
    for (int reg = 0; reg < 4; ++reg) {
        int rr = (w * 16 + quad * 4 + reg) * 136;
        aS[rr + l16]      = (_Float16)c0[reg];
        aS[rr + 16 + l16] = (_Float16)c1[reg];
        aS[rr + 32 + l16] = (_Float16)c2[reg];
    }
    __syncthreads();
    // h2 store: 64 rows x 40 f16 = 320 uint4 tasks
    for (int fi = t; fi < 320; fi += 256) {
        int r = fi / 5, s = fi - r * 5;
        int n = row0 + r;
        if (n < N_NODES) {
            uint4 v = *(uint4*)&aS[r * 136 + s * 8];
            *(uint4*)&h2h[(size_t)n * 40 + s * 8] = v;
        }
    }
    // fused att2 logits: 4 threads per row, 10 cols each, shfl reduce
    int r = t >> 2, q = t & 3;
    int n = row0 + r;
    float ps = 0.f, pd = 0.f;
    #pragma unroll
    for (int i = 0; i < 10; ++i) {
        int cc = q * 10 + i;
        float v = (float)aS[r * 136 + cc];
        ps += v * asld[cc]; pd += v * adld[cc];
    }
    ps += __shfl_xor(ps, 1); ps += __shfl_xor(ps, 2);
    pd += __shfl_xor(pd, 1); pd += __shfl_xor(pd, 2);
    if (q == 0 && n < N_NODES) { als[n] = ps; ald[n] = pd; }
}

// ===== layer2 fused single-pass, masked 12-blocks (4 per slot, no serial tail) =====
__global__ __launch_bounds__(256) void agg2_kernel(const int* __restrict__ deg_,
                                                   const unsigned short* __restrict__ csr16,
                                                   const float* __restrict__ als,
                                                   const float* __restrict__ ald,
                                                   const unsigned short* __restrict__ h2h,
                                                   const float* __restrict__ b2,
                                                   float* __restrict__ out) {
    int wv   = threadIdx.x >> 6;
    int lane = threadIdx.x & 63;
    int d    = blockIdx.x * 4 + wv;
    int dg   = min(deg_[d] + 1, CAP);      // +1: self-loop at slot 0
    int base = d * CAP;
    float aldd = ald[d];

    int slot = lane / 20;              // 0..2 active, 3 idle
    int idx  = lane - slot * 20;       // channel pair 0..19
    int sfirst = (int)csr16[base];
    float sm = 0.f, acc0 = 0.f, acc1 = 0.f;
    if (lane < 60) {
        #pragma unroll 2
        for (int jb = 0; jb < dg; jb += 12) {
            int ss[4]; unsigned hv[4]; float ww[4];
            #pragma unroll
            for (int i = 0; i < 4; ++i) {
                int jj = jb + slot + 3 * i;
                ss[i] = (jj < dg) ? (int)csr16[base + jj] : sfirst;
            }
            #pragma unroll
            for (int i = 0; i < 4; ++i)
                hv[i] = *(const unsigned*)(h2h + (size_t)ss[i] * 40 + 2 * idx);
            #pragma unroll
            for (int i = 0; i < 4; ++i) {
                int jj = jb + slot + 3 * i;
                float w = __expf(leaky(als[ss[i]] + aldd));
                ww[i] = (jj < dg) ? w : 0.f;
            }
            #pragma unroll
            for (int i = 0; i < 4; ++i) {
                float2 f = unp2h(hv[i]);
                acc0 += f.x * ww[i]; acc1 += f.y * ww[i]; sm += ww[i];
            }
        }
    }
    // reduce sm/acc across the 3 slots: lanes idx, idx+20, idx+40
    float s1 = __shfl(sm,   idx + 20), s2 = __shfl(sm,   idx + 40);
    float t0 = __shfl(acc0, idx + 20), t1 = __shfl(acc0, idx + 40);
    float u0 = __shfl(acc1, idx + 20), u1 = __shfl(acc1, idx + 40);
    sm += s1 + s2; acc0 += t0 + t1; acc1 += u0 + u1;
    if (lane < 20) {
        float inv = 1.f / (sm + 1e-16f);
        float2 o = make_float2(acc0 * inv + b2[2 * lane], acc1 * inv + b2[2 * lane + 1]);
        *(float2*)&out[(size_t)d * 40 + 2 * lane] = o;
    }
}

// ================= workspace layout (float-sized slots) =================
constexpr size_t OFF_H1H    = 0;          // h1 f16 (3.2M slots); h2 overlays after agg1
constexpr size_t OFF_OUT1   = 3200000;    // out1 f16 (3.2M slots)
constexpr size_t OFF_ALS1   = 6400000;    // 200,000 (als2 overlays)
constexpr size_t OFF_ALD1   = 6600000;    // 200,000 (ald2 overlays)
constexpr size_t OFF_W1T    = 6800000;    // w1t f16 [128][128] = 8192 float slots
constexpr size_t OFF_W2T    = 6808192;    // w2t f16 [40][128]  = 2560 float slots
constexpr size_t OFF_DEG    = 6860000;    // 50,000 ints
constexpr size_t OFF_CSRF   = 6920000;    // 50,000*64 u16 = 1.6M float slots
constexpr size_t WS_FLOATS  = 10120000;   // 40.5 MB

extern "C" void kernel_launch(void* const* d_in, const int* in_sizes, int n_in,
                              void* d_out, int out_size, void* d_ws, size_t ws_size,
                              hipStream_t stream) {
    const float* x   = (const float*)d_in[0];
    const int*   ei  = (const int*)  d_in[1];
    const float* W1  = (const float*)d_in[2];
    const float* as1 = (const float*)d_in[3];
    const float* ad1 = (const float*)d_in[4];
    const float* b1  = (const float*)d_in[5];
    const float* W2  = (const float*)d_in[6];
    const float* as2 = (const float*)d_in[7];
    const float* ad2 = (const float*)d_in[8];
    const float* b2  = (const float*)d_in[9];
    float* out = (float*)d_out;

    if (ws_size < WS_FLOATS * sizeof(float)) return;

    float* ws = (float*)d_ws;
    unsigned short* h1h   = (unsigned short*)(ws + OFF_H1H);
    unsigned short* h2h   = (unsigned short*)(ws + OFF_H1H);   // overlay, h1 dead after agg1
    unsigned short* out1h = (unsigned short*)(ws + OFF_OUT1);
    float* als1    = ws + OFF_ALS1;
    float* ald1    = ws + OFF_ALD1;
    float* als2    = ws + OFF_ALS1;   // overlay, dead after agg1
    float* ald2    = ws + OFF_ALD1;   // overlay
    _Float16* w1t  = (_Float16*)(ws + OFF_W1T);
    _Float16* w2t  = (_Float16*)(ws + OFF_W2T);
    int*   deg     = (int*)(ws + OFF_DEG);
    unsigned short* csr16 = (unsigned short*)(ws + OFF_CSRF);

    // ---- prep (deg=0 + W transposes), then fused [link->CSR || gemm1] ----
    prep_kernel<<<280, 256, 0, stream>>>(W1, W2, deg, w1t, w2t);
    gemm1_link_kernel<<<G1_BLOCKS + LINK_BLOCKS, 256, 0, stream>>>(
        x, w1t, as1, ad1, h1h, als1, ald1, ei, deg, csr16);

    // ---- layer 1 aggregate ----
    agg1_kernel<<<N_NODES / 4, 256, 0, stream>>>(deg, csr16, als1,
                                                 (const float4*)ald1,
                                                 h1h, b1, out1h);

    // ---- layer 2 ----
    gemm2_kernel<<<cdiv(N_NODES, 64), 256, 0, stream>>>(out1h, w2t, as2, ad2, h2h, als2, ald2);
    agg2_kernel<<<N_NODES / 4, 256, 0, stream>>>(deg, csr16, als2, ald2, h2h, b2, out);
}

// Round 6
// 210.437 us; speedup vs baseline: 1.2702x; 1.0679x over previous
//
#include <hip/hip_runtime.h>
#include <hip/hip_bf16.h>
#include <hip/hip_fp16.h>
#include <math.h>

// Problem constants
constexpr int N_NODES = 50000;
constexpr int E_EDGES = 800000;
constexpr float NEG_SLOPE = 0.2f;
constexpr int CAP = 64;   // fixed CSR capacity/dst. deg ~ Poisson(16)+1; P(>63)~1e-17.
constexpr int G1_BLOCKS   = (N_NODES + 63) / 64;        // 782 gemm1-role blocks
constexpr int LINK_BLOCKS = (E_EDGES + 255) / 256;      // 3125 link-role blocks (1 edge/thr)

typedef _Float16 half8 __attribute__((ext_vector_type(8)));
typedef _Float16 half2v __attribute__((ext_vector_type(2)));
typedef float    floatx4 __attribute__((ext_vector_type(4)));

static inline int cdiv(long long a, int b) { return (int)((a + b - 1) / b); }

__device__ inline float leaky(float a) { return a > 0.f ? a : NEG_SLOPE * a; }
__device__ inline unsigned pack2h(float a, float b) {
    union { _Float16 h[2]; unsigned u; } p;
    p.h[0] = (_Float16)a; p.h[1] = (_Float16)b; return p.u;
}
__device__ inline float2 unp2h(unsigned u) {
    __half2 hh = *reinterpret_cast<__half2*>(&u);
    return __half22float2(hh);
}
__device__ inline float sel4(const float4& v, int h) {
    float a = (h & 2) ? v.z : v.x;
    float b = (h & 2) ? v.w : v.y;
    return (h & 1) ? b : a;
}

// ====== prep: zero deg + transpose W1/W2 to f16 [col][k] ======
// w1t[c*128+k] = W1[k][c]  (c<128, k<128);  w2t[c*128+k] = W2[k][c]  (c<40, k<128)
__global__ __launch_bounds__(256) void prep_kernel(const float* __restrict__ W1,
                                                   const float* __restrict__ W2,
                                                   int* __restrict__ deg,
                                                   _Float16* __restrict__ w1t,
                                                   _Float16* __restrict__ w2t) {
    int b = blockIdx.x, t = threadIdx.x;
    if (b < 196) {                          // zero deg
        int i = b * 256 + t;
        if (i < N_NODES) deg[i] = 0;
        return;
    }
    if (b < 196 + 64) {                     // W1 transpose: 16384 elems
        int idx = (b - 196) * 256 + t;
        int k = idx >> 7, c = idx & 127;    // read coalesced over c
        w1t[c * 128 + k] = (_Float16)W1[k * 128 + c];
        return;
    }
    {                                       // W2 transpose: 5120 elems (20 blocks)
        int idx = (b - 260) * 256 + t;
        int k = idx / 40, c = idx - k * 40;
        w2t[c * 128 + k] = (_Float16)W2[k * 40 + c];
    }
}

// ====== Fused: GEMM1 (MFMA f16)+att1 (blocks < G1_BLOCKS) ∥ link (rest) ======
// R21: exact R18 structure (measured best: 18.4KB LDS, direct-slot CSR, gemm-first,
// 1 edge/thread) + NON-TEMPORAL csr16 scatter. The 2B scatter stores all land in
// one 128B line per dst but from ~16 different CUs/XCDs -> RFO line bouncing was
// 46MB of WRITE amplification (61MB observed vs 15MB logical). nt store skips L2
// allocate/ownership; nt loads keep the ei stream out of L2.
__global__ __launch_bounds__(256, 8) void gemm1_link_kernel(const float* __restrict__ x,
                                                            const _Float16* __restrict__ w1t,
                                                            const float* __restrict__ as1,
                                                            const float* __restrict__ ad1,
                                                            unsigned short* __restrict__ h1h,
                                                            float* __restrict__ als,
                                                            float* __restrict__ ald,
                                                            const int* __restrict__ ei,
                                                            int* __restrict__ deg,
                                                            unsigned short* __restrict__ csr16) {
    __shared__ _Float16 xS[64 * 136];    // 17.4 KB (X f16; reused as C buffer)
    __shared__ float asld[128], adld[128];
    int t = threadIdx.x;

    if (blockIdx.x >= G1_BLOCKS) {       // ---- link role: 1 edge per thread ----
        int e = (blockIdx.x - G1_BLOCKS) * 256 + t;
        if (e < E_EDGES) {
            int s = __builtin_nontemporal_load(&ei[e]);
            int d = __builtin_nontemporal_load(&ei[E_EDGES + e]);
            int slot = atomicAdd(&deg[d], 1) + 1;   // slot 0 reserved for self-loop
            if (slot < CAP)
                __builtin_nontemporal_store((unsigned short)s, &csr16[d * CAP + slot]);
        }
        return;
    }

    // ---- gemm1 role ----
    int row0 = blockIdx.x * 64;
    if (t < 128) { asld[t] = as1[t]; adld[t] = ad1[t]; }
    // stage X (f32 -> f16), full 128-K
    #pragma unroll
    for (int i = 0; i < 8; ++i) {
        int fi = i * 256 + t;            // 0..2047
        int r = fi >> 5, c4 = (fi & 31) * 4;
        int gr = row0 + r;
        float4 v = make_float4(0.f, 0.f, 0.f, 0.f);
        if (gr < N_NODES) v = *(const float4*)&x[(size_t)gr * 128 + c4];
        union { _Float16 h[4]; uint2 u; } pk;
        pk.h[0] = (_Float16)v.x; pk.h[1] = (_Float16)v.y;
        pk.h[2] = (_Float16)v.z; pk.h[3] = (_Float16)v.w;
        *(uint2*)&xS[r * 136 + c4] = pk.u;
    }
    __syncthreads();

    int w = t >> 6, lane = t & 63, quad = lane >> 4, l16 = lane & 15;
    floatx4 z = {0.f, 0.f, 0.f, 0.f};
    floatx4 c[4][2];
    #pragma unroll
    for (int rt = 0; rt < 4; ++rt) { c[rt][0] = z; c[rt][1] = z; }

    const _Float16* wt0 = w1t + (size_t)(w * 32 + l16) * 128;   // column (w*32+l16)
    const _Float16* wt1 = wt0 + 16 * 128;                       // column +16
    #pragma unroll
    for (int ks = 0; ks < 4; ++ks) {
        int kg = ks * 32 + quad * 8;
        half8 b0 = *(const half8*)&wt0[kg];
        half8 b1 = *(const half8*)&wt1[kg];
        #pragma unroll
        for (int rt = 0; rt < 4; ++rt) {
            half8 a = *(const half8*)&xS[(rt * 16 + l16) * 136 + kg];
            c[rt][0] = __builtin_amdgcn_mfma_f32_16x16x32_f16(a, b0, c[rt][0], 0, 0, 0);
            c[rt][1] = __builtin_amdgcn_mfma_f32_16x16x32_f16(a, b1, c[rt][1], 0, 0, 0);
        }
    }
    __syncthreads();
    // transpose C into xS region as f16 (64 rows x stride 136; 8704 slots exactly)
    _Float16* cbuf = xS;
    #pragma unroll
    for (int rt = 0; rt < 4; ++rt)
        #pragma unroll
        for (int ctl = 0; ctl < 2; ++ctl)
            #pragma unroll
            for (int reg = 0; reg < 4; ++reg)
                cbuf[(rt * 16 + quad * 4 + reg) * 136 + (w * 32 + ctl * 16 + l16)]
                    = (_Float16)c[rt][ctl][reg];
    __syncthreads();
    // epilogue: thread t -> (row r, head hq); store h1 row segment + logits + self-loop
    int r = t >> 2, hq = t & 3;
    int n = row0 + r;
    if (n < N_NODES) {
        if (hq == 0) csr16[n * CAP] = (unsigned short)n;   // self-loop slot 0
        float ps = 0.f, pd = 0.f;
        #pragma unroll
        for (int i = 0; i < 4; ++i) {
            uint4 uv = *(uint4*)&cbuf[r * 136 + hq * 32 + i * 8];
            *(uint4*)&h1h[(size_t)n * 128 + hq * 32 + i * 8] = uv;
            union { uint4 u; _Float16 h[8]; } cv; cv.u = uv;
            #pragma unroll
            for (int k = 0; k < 8; ++k) {
                float v = (float)cv.h[k];
                ps += v * asld[hq * 32 + i * 8 + k];
                pd += v * adld[hq * 32 + i * 8 + k];
            }
        }
        als[n * 4 + hq] = ps;
        ald[n * 4 + hq] = pd;
    }
}

// ===== layer1 fused single-pass softmax-aggregate =====
// Weights: lane (we=lane&15, wh=lane>>4) computes exp for (edge we, head wh) -- ONE
// exp issue covers all 64 (edge,head) pairs of a 16-edge block.
// Gathers: split-wave (lanes 0-31 even edges / 32-63 odd), uint2 channel-quad per lane.
// unroll 2 on the j-loop doubles independent gather chains in flight.
__global__ __launch_bounds__(256) void agg1_kernel(const int* __restrict__ deg_,
                                                   const unsigned short* __restrict__ csr16,
                                                   const float* __restrict__ als,
                                                   const float4* __restrict__ ald4,
                                                   const unsigned short* __restrict__ h1h,
                                                   const float* __restrict__ b1,
                                                   unsigned short* __restrict__ out1h) {
    int wv   = threadIdx.x >> 6;
    int lane = threadIdx.x & 63;
    int half = lane >> 5;                     // 0: even edges, 1: odd edges
    int l    = lane & 31;                     // channel quad: channels 4l..4l+3
    int myhead = l >> 3;                      // 32 channels per head
    int we   = lane & 15;                     // weight-role: edge offset
    int wh   = lane >> 4;                     // weight-role: head
    int d    = blockIdx.x * 4 + wv;           // grid exactly covers N
    int dg   = min(deg_[d] + 1, CAP);         // +1: self-loop at slot 0
    int base = d * CAP;
    float4 aldd = ald4[d];
    float d_hw = sel4(aldd, wh);              // weight-role ald component (loop-invariant)

    float sm = 0.f;
    float acc[4] = {0.f, 0.f, 0.f, 0.f};
    int sfirst = (int)csr16[base];            // self-loop: always valid
    #pragma unroll 2
    for (int j = 0; j < dg; j += 16) {
        // ---- weight phase: one (edge,head) per lane ----
        int s_w = (int)csr16[base + j + we];  // lanes share a 32B segment (broadcast)
        float av = als[s_w * 4 + wh];         // L2-resident 800KB table gather
        float wgt = (j + we < dg) ? __expf(leaky(av + d_hw)) : 0.f;
        // ---- index phase for my half's 8 edges ----
        uint4 blkA = *(const uint4*)&csr16[base + j];       // 16B aligned
        uint4 blkB = *(const uint4*)&csr16[base + j + 8];
        unsigned bw[8] = { blkA.x, blkA.y, blkA.z, blkA.w,
                           blkB.x, blkB.y, blkB.z, blkB.w };
        int ss[8];
        #pragma unroll
        for (int p = 0; p < 8; ++p) {
            unsigned b = __builtin_amdgcn_readfirstlane(bw[p]);
            int e0 = (int)(b & 0xffff), e1 = (int)(b >> 16);
            int mys = half ? e1 : e0;
            if (j + 2 * p + half >= dg) mys = sfirst;
            ss[p] = mys;
        }
        uint2 hv[8];
        #pragma unroll
        for (int p = 0; p < 8; ++p)
            hv[p] = *(const uint2*)(h1h + ((size_t)ss[p] << 7) + 4 * l);
        // ---- fetch my 8 weights via bpermute ----
        float ww[8];
        #pragma unroll
        for (int p = 0; p < 8; ++p) {
            ww[p] = __shfl(wgt, 16 * myhead + 2 * p + half);
            sm += ww[p];
        }
        half2v hacc0 = { (_Float16)0.f, (_Float16)0.f };
        half2v hacc1 = { (_Float16)0.f, (_Float16)0.f };
        #pragma unroll
        for (int p = 0; p < 8; ++p) {
            half2v v0 = *reinterpret_cast<half2v*>(&hv[p].x);
            half2v v1 = *reinterpret_cast<half2v*>(&hv[p].y);
            _Float16 hw = (_Float16)ww[p];
            half2v hwv = { hw, hw };
            hacc0 += v0 * hwv;                // v_pk_fma_f16
            hacc1 += v1 * hwv;
        }
        acc[0] += (float)hacc0[0]; acc[1] += (float)hacc0[1];
        acc[2] += (float)hacc1[0]; acc[3] += (float)hacc1[1];
    }
    // cross-half reduce (lanes l and l+32 hold same channels, disjoint edges)
    sm += __shfl_xor(sm, 32);
    #pragma unroll
    for (int k = 0; k < 4; ++k) acc[k] += __shfl_xor(acc[k], 32);
    if (half == 0) {
        float inv = 1.f / (sm + 1e-16f);
        float v[4];
        #pragma unroll
        for (int k = 0; k < 4; ++k) {
            v[k] = acc[k] * inv + b1[4 * l + k];
            v[k] = v[k] > 0.f ? v[k] : __expf(v[k]) - 1.f;
        }
        uint2 o;
        o.x = pack2h(v[0], v[1]);
        o.y = pack2h(v[2], v[3]);
        *(uint2*)&out1h[(size_t)d * 128 + 4 * l] = o;
    }
}

// ===== GEMM2 (MFMA f16) + fused att2: h2h[N,40] f16, als2/ald2[N] =====
// B-fragments are half8 loads from pre-transposed w2t [40][128] (10KB).
__global__ __launch_bounds__(256, 8) void gemm2_kernel(const unsigned short* __restrict__ out1h,
                                                       const _Float16* __restrict__ w2t,
                                                       const float* __restrict__ as2,
                                                       const float* __restrict__ ad2,
                                                       unsigned short* __restrict__ h2h,
                                                       float* __restrict__ als,
                                                       float* __restrict__ ald) {
    __shared__ _Float16 aS[64 * 136];    // staging + C transpose
    __shared__ float asld[40], adld[40];
    int t = threadIdx.x;
    int row0 = blockIdx.x * 64;
    if (t < 40) { asld[t] = as2[t]; adld[t] = ad2[t]; }
    // stage A (f16 copy)
    #pragma unroll
    for (int i = 0; i < 4; ++i) {
        int fi = i * 256 + t;             // 0..1023
        int r = fi >> 4, s8 = (fi & 15) * 8;
        int gr = row0 + r;
        uint4 v = make_uint4(0u, 0u, 0u, 0u);
        if (gr < N_NODES) v = *(const uint4*)&out1h[(size_t)gr * 128 + s8];
        *(uint4*)&aS[r * 136 + s8] = v;
    }
    __syncthreads();

    int w = t >> 6, lane = t & 63, quad = lane >> 4, l16 = lane & 15;
    floatx4 z = {0.f, 0.f, 0.f, 0.f};
    floatx4 c0 = z, c1 = z, c2 = z;
    int n2 = (l16 < 8) ? 32 + l16 : 39;    // clamp: cols 40..47 feed discarded output
    const _Float16* wb0 = w2t + (size_t)l16 * 128;
    const _Float16* wb1 = w2t + (size_t)(16 + l16) * 128;
    const _Float16* wb2 = w2t + (size_t)n2 * 128;
    #pragma unroll
    for (int ks = 0; ks < 4; ++ks) {
        int kg = ks * 32 + quad * 8;
        half8 b0 = *(const half8*)&wb0[kg];
        half8 b1 = *(const half8*)&wb1[kg];
        half8 b2 = *(const half8*)&wb2[kg];
        half8 a  = *(const half8*)&aS[(w * 16 + l16) * 136 + kg];
        c0 = __builtin_amdgcn_mfma_f32_16x16x32_f16(a, b0, c0, 0, 0, 0);
        c1 = __builtin_amdgcn_mfma_f32_16x16x32_f16(a, b1, c1, 0, 0, 0);
        c2 = __builtin_amdgcn_mfma_f32_16x16x32_f16(a, b2, c2, 0, 0, 0);
    }
    __syncthreads();
    #pragma unroll
    for (int reg = 0; reg < 4; ++reg) {
        int rr = (w * 16 + quad * 4 + reg) * 136;
        aS[rr + l16]      = (_Float16)c0[reg];
        aS[rr + 16 + l16] = (_Float16)c1[reg];
        aS[rr + 32 + l16] = (_Float16)c2[reg];
    }
    __syncthreads();
    // h2 store: 64 rows x 40 f16 = 320 uint4 tasks
    for (int fi = t; fi < 320; fi += 256) {
        int r = fi / 5, s = fi - r * 5;
        int n = row0 + r;
        if (n < N_NODES) {
            uint4 v = *(uint4*)&aS[r * 136 + s * 8];
            *(uint4*)&h2h[(size_t)n * 40 + s * 8] = v;
        }
    }
    // fused att2 logits: 4 threads per row, 10 cols each, shfl reduce
    int r = t >> 2, q = t & 3;
    int n = row0 + r;
    float ps = 0.f, pd = 0.f;
    #pragma unroll
    for (int i = 0; i < 10; ++i) {
        int cc = q * 10 + i;
        float v = (float)aS[r * 136 + cc];
        ps += v * asld[cc]; pd += v * adld[cc];
    }
    ps += __shfl_xor(ps, 1); ps += __shfl_xor(ps, 2);
    pd += __shfl_xor(pd, 1); pd += __shfl_xor(pd, 2);
    if (q == 0 && n < N_NODES) { als[n] = ps; ald[n] = pd; }
}

// ===== layer2 fused single-pass, masked 12-blocks (4 per slot, no serial tail) =====
__global__ __launch_bounds__(256) void agg2_kernel(const int* __restrict__ deg_,
                                                   const unsigned short* __restrict__ csr16,
                                                   const float* __restrict__ als,
                                                   const float* __restrict__ ald,
                                                   const unsigned short* __restrict__ h2h,
                                                   const float* __restrict__ b2,
                                                   float* __restrict__ out) {
    int wv   = threadIdx.x >> 6;
    int lane = threadIdx.x & 63;
    int d    = blockIdx.x * 4 + wv;
    int dg   = min(deg_[d] + 1, CAP);      // +1: self-loop at slot 0
    int base = d * CAP;
    float aldd = ald[d];

    int slot = lane / 20;              // 0..2 active, 3 idle
    int idx  = lane - slot * 20;       // channel pair 0..19
    int sfirst = (int)csr16[base];
    float sm = 0.f, acc0 = 0.f, acc1 = 0.f;
    if (lane < 60) {
        #pragma unroll 2
        for (int jb = 0; jb < dg; jb += 12) {
            int ss[4]; unsigned hv[4]; float ww[4];
            #pragma unroll
            for (int i = 0; i < 4; ++i) {
                int jj = jb + slot + 3 * i;
                ss[i] = (jj < dg) ? (int)csr16[base + jj] : sfirst;
            }
            #pragma unroll
            for (int i = 0; i < 4; ++i)
                hv[i] = *(const unsigned*)(h2h + (size_t)ss[i] * 40 + 2 * idx);
            #pragma unroll
            for (int i = 0; i < 4; ++i) {
                int jj = jb + slot + 3 * i;
                float w = __expf(leaky(als[ss[i]] + aldd));
                ww[i] = (jj < dg) ? w : 0.f;
            }
            #pragma unroll
            for (int i = 0; i < 4; ++i) {
                float2 f = unp2h(hv[i]);
                acc0 += f.x * ww[i]; acc1 += f.y * ww[i]; sm += ww[i];
            }
        }
    }
    // reduce sm/acc across the 3 slots: lanes idx, idx+20, idx+40
    float s1 = __shfl(sm,   idx + 20), s2 = __shfl(sm,   idx + 40);
    float t0 = __shfl(acc0, idx + 20), t1 = __shfl(acc0, idx + 40);
    float u0 = __shfl(acc1, idx + 20), u1 = __shfl(acc1, idx + 40);
    sm += s1 + s2; acc0 += t0 + t1; acc1 += u0 + u1;
    if (lane < 20) {
        float inv = 1.f / (sm + 1e-16f);
        float2 o = make_float2(acc0 * inv + b2[2 * lane], acc1 * inv + b2[2 * lane + 1]);
        *(float2*)&out[(size_t)d * 40 + 2 * lane] = o;
    }
}

// ================= workspace layout (float-sized slots) =================
constexpr size_t OFF_H1H    = 0;          // h1 f16 (3.2M slots); h2 overlays after agg1
constexpr size_t OFF_OUT1   = 3200000;    // out1 f16 (3.2M slots)
constexpr size_t OFF_ALS1   = 6400000;    // 200,000 (als2 overlays)
constexpr size_t OFF_ALD1   = 6600000;    // 200,000 (ald2 overlays)
constexpr size_t OFF_W1T    = 6800000;    // w1t f16 [128][128] = 8192 float slots
constexpr size_t OFF_W2T    = 6808192;    // w2t f16 [40][128]  = 2560 float slots
constexpr size_t OFF_DEG    = 6860000;    // 50,000 ints
constexpr size_t OFF_CSRF   = 6920000;    // 50,000*64 u16 = 1.6M float slots
constexpr size_t WS_FLOATS  = 10120000;   // 40.5 MB

extern "C" void kernel_launch(void* const* d_in, const int* in_sizes, int n_in,
                              void* d_out, int out_size, void* d_ws, size_t ws_size,
                              hipStream_t stream) {
    const float* x   = (const float*)d_in[0];
    const int*   ei  = (const int*)  d_in[1];
    const float* W1  = (const float*)d_in[2];
    const float* as1 = (const float*)d_in[3];
    const float* ad1 = (const float*)d_in[4];
    const float* b1  = (const float*)d_in[5];
    const float* W2  = (const float*)d_in[6];
    const float* as2 = (const float*)d_in[7];
    const float* ad2 = (const float*)d_in[8];
    const float* b2  = (const float*)d_in[9];
    float* out = (float*)d_out;

    if (ws_size < WS_FLOATS * sizeof(float)) return;

    float* ws = (float*)d_ws;
    unsigned short* h1h   = (unsigned short*)(ws + OFF_H1H);
    unsigned short* h2h   = (unsigned short*)(ws + OFF_H1H);   // overlay, h1 dead after agg1
    unsigned short* out1h = (unsigned short*)(ws + OFF_OUT1);
    float* als1    = ws + OFF_ALS1;
    float* ald1    = ws + OFF_ALD1;
    float* als2    = ws + OFF_ALS1;   // overlay, dead after agg1
    float* ald2    = ws + OFF_ALD1;   // overlay
    _Float16* w1t  = (_Float16*)(ws + OFF_W1T);
    _Float16* w2t  = (_Float16*)(ws + OFF_W2T);
    int*   deg     = (int*)(ws + OFF_DEG);
    unsigned short* csr16 = (unsigned short*)(ws + OFF_CSRF);

    // ---- prep (deg=0 + W transposes), then fused [gemm1 || link->CSR direct] ----
    prep_kernel<<<280, 256, 0, stream>>>(W1, W2, deg, w1t, w2t);
    gemm1_link_kernel<<<G1_BLOCKS + LINK_BLOCKS, 256, 0, stream>>>(
        x, w1t, as1, ad1, h1h, als1, ald1, ei, deg, csr16);

    // ---- layer 1 aggregate ----
    agg1_kernel<<<N_NODES / 4, 256, 0, stream>>>(deg, csr16, als1,
                                                 (const float4*)ald1,
                                                 h1h, b1, out1h);

    // ---- layer 2 ----
    gemm2_kernel<<<cdiv(N_NODES, 64), 256, 0, stream>>>(out1h, w2t, as2, ad2, h2h, als2, ald2);
    agg2_kernel<<<N_NODES / 4, 256, 0, stream>>>(deg, csr16, als2, ald2, h2h, b2, out);
}

// Round 7
// 203.745 us; speedup vs baseline: 1.3120x; 1.0328x over previous
//
#include <hip/hip_runtime.h>
#include <hip/hip_bf16.h>
#include <hip/hip_fp16.h>
#include <math.h>

// Problem constants
constexpr int N_NODES = 50000;
constexpr int E_EDGES = 800000;
constexpr float NEG_SLOPE = 0.2f;
constexpr int CAP = 64;   // fixed CSR capacity/dst. deg ~ Poisson(16)+1; P(>63)~1e-17.
constexpr int G1_BLOCKS   = (N_NODES + 63) / 64;        // 782 gemm1-role blocks
// R22: link role is XCD-sharded: 8 dst-ranges x 391 chunks of 2048 edges.
constexpr int LINK_CHUNKS = (E_EDGES + 2047) / 2048;    // 391
constexpr int LINK_BLOCKS = LINK_CHUNKS * 8;            // 3128 (same wave count as R18)
constexpr int RANGE_SZ    = N_NODES / 8;                // 6250 dsts per range

typedef _Float16 half8 __attribute__((ext_vector_type(8)));
typedef _Float16 half2v __attribute__((ext_vector_type(2)));
typedef float    floatx4 __attribute__((ext_vector_type(4)));

static inline int cdiv(long long a, int b) { return (int)((a + b - 1) / b); }

__device__ inline float leaky(float a) { return a > 0.f ? a : NEG_SLOPE * a; }
__device__ inline unsigned pack2h(float a, float b) {
    union { _Float16 h[2]; unsigned u; } p;
    p.h[0] = (_Float16)a; p.h[1] = (_Float16)b; return p.u;
}
__device__ inline float2 unp2h(unsigned u) {
    __half2 hh = *reinterpret_cast<__half2*>(&u);
    return __half22float2(hh);
}
__device__ inline float sel4(const float4& v, int h) {
    float a = (h & 2) ? v.z : v.x;
    float b = (h & 2) ? v.w : v.y;
    return (h & 1) ? b : a;
}

// ====== prep: zero deg + transpose W1/W2 to f16 [col][k] ======
// w1t[c*128+k] = W1[k][c]  (c<128, k<128);  w2t[c*128+k] = W2[k][c]  (c<40, k<128)
__global__ __launch_bounds__(256) void prep_kernel(const float* __restrict__ W1,
                                                   const float* __restrict__ W2,
                                                   int* __restrict__ deg,
                                                   _Float16* __restrict__ w1t,
                                                   _Float16* __restrict__ w2t) {
    int b = blockIdx.x, t = threadIdx.x;
    if (b < 196) {                          // zero deg
        int i = b * 256 + t;
        if (i < N_NODES) deg[i] = 0;
        return;
    }
    if (b < 196 + 64) {                     // W1 transpose: 16384 elems
        int idx = (b - 196) * 256 + t;
        int k = idx >> 7, c = idx & 127;    // read coalesced over c
        w1t[c * 128 + k] = (_Float16)W1[k * 128 + c];
        return;
    }
    {                                       // W2 transpose: 5120 elems (20 blocks)
        int idx = (b - 260) * 256 + t;
        int k = idx / 40, c = idx - k * 40;
        w2t[c * 128 + k] = (_Float16)W2[k * 40 + c];
    }
}

// ====== Fused: GEMM1 (MFMA f16)+att1 (blocks < G1_BLOCKS) ∥ link (rest) ======
// R22: XCD-sharded link. Evidence: WRITE_SIZE 61-64MB vs ~15MB logical = csr16
// 128B lines bouncing between ~16 writers spread over 8 XCDs; nt store didn't
// help (R21). Fix the SHARDING instead: link block lb handles dst range (lb&7)
// and edge chunk (lb>>3). Under round-robin blockIdx->XCD dispatch all writers
// of a range live on ONE XCD -> deg atomics + csr16 lines stay in local L2.
// Each thread scans 8 edges (4x int4 coalesced loads), atomics the ~1 match:
// same 800K-thread wave count as R18 (not R17's starvation).
__global__ __launch_bounds__(256, 8) void gemm1_link_kernel(const float* __restrict__ x,
                                                            const _Float16* __restrict__ w1t,
                                                            const float* __restrict__ as1,
                                                            const float* __restrict__ ad1,
                                                            unsigned short* __restrict__ h1h,
                                                            float* __restrict__ als,
                                                            float* __restrict__ ald,
                                                            const int* __restrict__ ei,
                                                            int* __restrict__ deg,
                                                            unsigned short* __restrict__ csr16) {
    __shared__ _Float16 xS[64 * 136];    // 17.4 KB (X f16; reused as C buffer)
    __shared__ float asld[128], adld[128];
    int t = threadIdx.x;

    if (blockIdx.x >= G1_BLOCKS) {       // ---- link role: XCD-sharded ----
        int lb    = blockIdx.x - G1_BLOCKS;
        int range = lb & 7;              // fixed XCD under round-robin dispatch
        int chunk = lb >> 3;
        int e0    = chunk * 2048 + t * 8;
        if (e0 < E_EDGES) {              // E%8==0 -> int4 reads never straddle E
            int4 sa = *(const int4*)&ei[e0];
            int4 sb = *(const int4*)&ei[e0 + 4];
            int4 da = *(const int4*)&ei[E_EDGES + e0];
            int4 db = *(const int4*)&ei[E_EDGES + e0 + 4];
            int ss[8] = { sa.x, sa.y, sa.z, sa.w, sb.x, sb.y, sb.z, sb.w };
            int dd[8] = { da.x, da.y, da.z, da.w, db.x, db.y, db.z, db.w };
            int dlo = range * RANGE_SZ, dhi = dlo + RANGE_SZ;
            #pragma unroll
            for (int j = 0; j < 8; ++j) {
                if (dd[j] >= dlo && dd[j] < dhi) {
                    int slot = atomicAdd(&deg[dd[j]], 1) + 1;  // slot 0 = self-loop
                    if (slot < CAP) csr16[dd[j] * CAP + slot] = (unsigned short)ss[j];
                }
            }
        }
        return;
    }

    // ---- gemm1 role ----
    int row0 = blockIdx.x * 64;
    if (t < 128) { asld[t] = as1[t]; adld[t] = ad1[t]; }
    // stage X (f32 -> f16), full 128-K
    #pragma unroll
    for (int i = 0; i < 8; ++i) {
        int fi = i * 256 + t;            // 0..2047
        int r = fi >> 5, c4 = (fi & 31) * 4;
        int gr = row0 + r;
        float4 v = make_float4(0.f, 0.f, 0.f, 0.f);
        if (gr < N_NODES) v = *(const float4*)&x[(size_t)gr * 128 + c4];
        union { _Float16 h[4]; uint2 u; } pk;
        pk.h[0] = (_Float16)v.x; pk.h[1] = (_Float16)v.y;
        pk.h[2] = (_Float16)v.z; pk.h[3] = (_Float16)v.w;
        *(uint2*)&xS[r * 136 + c4] = pk.u;
    }
    __syncthreads();

    int w = t >> 6, lane = t & 63, quad = lane >> 4, l16 = lane & 15;
    floatx4 z = {0.f, 0.f, 0.f, 0.f};
    floatx4 c[4][2];
    #pragma unroll
    for (int rt = 0; rt < 4; ++rt) { c[rt][0] = z; c[rt][1] = z; }

    const _Float16* wt0 = w1t + (size_t)(w * 32 + l16) * 128;   // column (w*32+l16)
    const _Float16* wt1 = wt0 + 16 * 128;                       // column +16
    #pragma unroll
    for (int ks = 0; ks < 4; ++ks) {
        int kg = ks * 32 + quad * 8;
        half8 b0 = *(const half8*)&wt0[kg];
        half8 b1 = *(const half8*)&wt1[kg];
        #pragma unroll
        for (int rt = 0; rt < 4; ++rt) {
            half8 a = *(const half8*)&xS[(rt * 16 + l16) * 136 + kg];
            c[rt][0] = __builtin_amdgcn_mfma_f32_16x16x32_f16(a, b0, c[rt][0], 0, 0, 0);
            c[rt][1] = __builtin_amdgcn_mfma_f32_16x16x32_f16(a, b1, c[rt][1], 0, 0, 0);
        }
    }
    __syncthreads();
    // transpose C into xS region as f16 (64 rows x stride 136; 8704 slots exactly)
    _Float16* cbuf = xS;
    #pragma unroll
    for (int rt = 0; rt < 4; ++rt)
        #pragma unroll
        for (int ctl = 0; ctl < 2; ++ctl)
            #pragma unroll
            for (int reg = 0; reg < 4; ++reg)
                cbuf[(rt * 16 + quad * 4 + reg) * 136 + (w * 32 + ctl * 16 + l16)]
                    = (_Float16)c[rt][ctl][reg];
    __syncthreads();
    // epilogue: thread t -> (row r, head hq); store h1 row segment + logits + self-loop
    int r = t >> 2, hq = t & 3;
    int n = row0 + r;
    if (n < N_NODES) {
        if (hq == 0) csr16[n * CAP] = (unsigned short)n;   // self-loop slot 0
        float ps = 0.f, pd = 0.f;
        #pragma unroll
        for (int i = 0; i < 4; ++i) {
            uint4 uv = *(uint4*)&cbuf[r * 136 + hq * 32 + i * 8];
            *(uint4*)&h1h[(size_t)n * 128 + hq * 32 + i * 8] = uv;
            union { uint4 u; _Float16 h[8]; } cv; cv.u = uv;
            #pragma unroll
            for (int k = 0; k < 8; ++k) {
                float v = (float)cv.h[k];
                ps += v * asld[hq * 32 + i * 8 + k];
                pd += v * adld[hq * 32 + i * 8 + k];
            }
        }
        als[n * 4 + hq] = ps;
        ald[n * 4 + hq] = pd;
    }
}

// ===== layer1 fused single-pass softmax-aggregate =====
// Weights: lane (we=lane&15, wh=lane>>4) computes exp for (edge we, head wh) -- ONE
// exp issue covers all 64 (edge,head) pairs of a 16-edge block.
// Gathers: split-wave (lanes 0-31 even edges / 32-63 odd), uint2 channel-quad per lane.
// unroll 2 on the j-loop doubles independent gather chains in flight.
__global__ __launch_bounds__(256) void agg1_kernel(const int* __restrict__ deg_,
                                                   const unsigned short* __restrict__ csr16,
                                                   const float* __restrict__ als,
                                                   const float4* __restrict__ ald4,
                                                   const unsigned short* __restrict__ h1h,
                                                   const float* __restrict__ b1,
                                                   unsigned short* __restrict__ out1h) {
    int wv   = threadIdx.x >> 6;
    int lane = threadIdx.x & 63;
    int half = lane >> 5;                     // 0: even edges, 1: odd edges
    int l    = lane & 31;                     // channel quad: channels 4l..4l+3
    int myhead = l >> 3;                      // 32 channels per head
    int we   = lane & 15;                     // weight-role: edge offset
    int wh   = lane >> 4;                     // weight-role: head
    int d    = blockIdx.x * 4 + wv;           // grid exactly covers N
    int dg   = min(deg_[d] + 1, CAP);         // +1: self-loop at slot 0
    int base = d * CAP;
    float4 aldd = ald4[d];
    float d_hw = sel4(aldd, wh);              // weight-role ald component (loop-invariant)

    float sm = 0.f;
    float acc[4] = {0.f, 0.f, 0.f, 0.f};
    int sfirst = (int)csr16[base];            // self-loop: always valid
    #pragma unroll 2
    for (int j = 0; j < dg; j += 16) {
        // ---- weight phase: one (edge,head) per lane ----
        int s_w = (int)csr16[base + j + we];  // lanes share a 32B segment (broadcast)
        float av = als[s_w * 4 + wh];         // L2-resident 800KB table gather
        float wgt = (j + we < dg) ? __expf(leaky(av + d_hw)) : 0.f;
        // ---- index phase for my half's 8 edges ----
        uint4 blkA = *(const uint4*)&csr16[base + j];       // 16B aligned
        uint4 blkB = *(const uint4*)&csr16[base + j + 8];
        unsigned bw[8] = { blkA.x, blkA.y, blkA.z, blkA.w,
                           blkB.x, blkB.y, blkB.z, blkB.w };
        int ss[8];
        #pragma unroll
        for (int p = 0; p < 8; ++p) {
            unsigned b = __builtin_amdgcn_readfirstlane(bw[p]);
            int e0 = (int)(b & 0xffff), e1 = (int)(b >> 16);
            int mys = half ? e1 : e0;
            if (j + 2 * p + half >= dg) mys = sfirst;
            ss[p] = mys;
        }
        uint2 hv[8];
        #pragma unroll
        for (int p = 0; p < 8; ++p)
            hv[p] = *(const uint2*)(h1h + ((size_t)ss[p] << 7) + 4 * l);
        // ---- fetch my 8 weights via bpermute ----
        float ww[8];
        #pragma unroll
        for (int p = 0; p < 8; ++p) {
            ww[p] = __shfl(wgt, 16 * myhead + 2 * p + half);
            sm += ww[p];
        }
        half2v hacc0 = { (_Float16)0.f, (_Float16)0.f };
        half2v hacc1 = { (_Float16)0.f, (_Float16)0.f };
        #pragma unroll
        for (int p = 0; p < 8; ++p) {
            half2v v0 = *reinterpret_cast<half2v*>(&hv[p].x);
            half2v v1 = *reinterpret_cast<half2v*>(&hv[p].y);
            _Float16 hw = (_Float16)ww[p];
            half2v hwv = { hw, hw };
            hacc0 += v0 * hwv;                // v_pk_fma_f16
            hacc1 += v1 * hwv;
        }
        acc[0] += (float)hacc0[0]; acc[1] += (float)hacc0[1];
        acc[2] += (float)hacc1[0]; acc[3] += (float)hacc1[1];
    }
    // cross-half reduce (lanes l and l+32 hold same channels, disjoint edges)
    sm += __shfl_xor(sm, 32);
    #pragma unroll
    for (int k = 0; k < 4; ++k) acc[k] += __shfl_xor(acc[k], 32);
    if (half == 0) {
        float inv = 1.f / (sm + 1e-16f);
        float v[4];
        #pragma unroll
        for (int k = 0; k < 4; ++k) {
            v[k] = acc[k] * inv + b1[4 * l + k];
            v[k] = v[k] > 0.f ? v[k] : __expf(v[k]) - 1.f;
        }
        uint2 o;
        o.x = pack2h(v[0], v[1]);
        o.y = pack2h(v[2], v[3]);
        *(uint2*)&out1h[(size_t)d * 128 + 4 * l] = o;
    }
}

// ===== GEMM2 (MFMA f16) + fused att2: h2h[N,40] f16, als2/ald2[N] =====
// B-fragments are half8 loads from pre-transposed w2t [40][128] (10KB).
__global__ __launch_bounds__(256, 8) void gemm2_kernel(const unsigned short* __restrict__ out1h,
                                                       const _Float16* __restrict__ w2t,
                                                       const float* __restrict__ as2,
                                                       const float* __restrict__ ad2,
                                                       unsigned short* __restrict__ h2h,
                                                       float* __restrict__ als,
                                                       float* __restrict__ ald) {
    __shared__ _Float16 aS[64 * 136];    // staging + C transpose
    __shared__ float asld[40], adld[40];
    int t = threadIdx.x;
    int row0 = blockIdx.x * 64;
    if (t < 40) { asld[t] = as2[t]; adld[t] = ad2[t]; }
    // stage A (f16 copy)
    #pragma unroll
    for (int i = 0; i < 4; ++i) {
        int fi = i * 256 + t;             // 0..1023
        int r = fi >> 4, s8 = (fi & 15) * 8;
        int gr = row0 + r;
        uint4 v = make_uint4(0u, 0u, 0u, 0u);
        if (gr < N_NODES) v = *(const uint4*)&out1h[(size_t)gr * 128 + s8];
        *(uint4*)&aS[r * 136 + s8] = v;
    }
    __syncthreads();

    int w = t >> 6, lane = t & 63, quad = lane >> 4, l16 = lane & 15;
    floatx4 z = {0.f, 0.f, 0.f, 0.f};
    floatx4 c0 = z, c1 = z, c2 = z;
    int n2 = (l16 < 8) ? 32 + l16 : 39;    // clamp: cols 40..47 feed discarded output
    const _Float16* wb0 = w2t + (size_t)l16 * 128;
    const _Float16* wb1 = w2t + (size_t)(16 + l16) * 128;
    const _Float16* wb2 = w2t + (size_t)n2 * 128;
    #pragma unroll
    for (int ks = 0; ks < 4; ++ks) {
        int kg = ks * 32 + quad * 8;
        half8 b0 = *(const half8*)&wb0[kg];
        half8 b1 = *(const half8*)&wb1[kg];
        half8 b2 = *(const half8*)&wb2[kg];
        half8 a  = *(const half8*)&aS[(w * 16 + l16) * 136 + kg];
        c0 = __builtin_amdgcn_mfma_f32_16x16x32_f16(a, b0, c0, 0, 0, 0);
        c1 = __builtin_amdgcn_mfma_f32_16x16x32_f16(a, b1, c1, 0, 0, 0);
        c2 = __builtin_amdgcn_mfma_f32_16x16x32_f16(a, b2, c2, 0, 0, 0);
    }
    __syncthreads();
    #pragma unroll
    for (int reg = 0; reg < 4; ++reg) {
        int rr = (w * 16 + quad * 4 + reg) * 136;
        aS[rr + l16]      = (_Float16)c0[reg];
        aS[rr + 16 + l16] = (_Float16)c1[reg];
        aS[rr + 32 + l16] = (_Float16)c2[reg];
    }
    __syncthreads();
    // h2 store: 64 rows x 40 f16 = 320 uint4 tasks
    for (int fi = t; fi < 320; fi += 256) {
        int r = fi / 5, s = fi - r * 5;
        int n = row0 + r;
        if (n < N_NODES) {
            uint4 v = *(uint4*)&aS[r * 136 + s * 8];
            *(uint4*)&h2h[(size_t)n * 40 + s * 8] = v;
        }
    }
    // fused att2 logits: 4 threads per row, 10 cols each, shfl reduce
    int r = t >> 2, q = t & 3;
    int n = row0 + r;
    float ps = 0.f, pd = 0.f;
    #pragma unroll
    for (int i = 0; i < 10; ++i) {
        int cc = q * 10 + i;
        float v = (float)aS[r * 136 + cc];
        ps += v * asld[cc]; pd += v * adld[cc];
    }
    ps += __shfl_xor(ps, 1); ps += __shfl_xor(ps, 2);
    pd += __shfl_xor(pd, 1); pd += __shfl_xor(pd, 2);
    if (q == 0 && n < N_NODES) { als[n] = ps; ald[n] = pd; }
}

// ===== layer2 fused single-pass, masked 12-blocks (4 per slot, no serial tail) =====
__global__ __launch_bounds__(256) void agg2_kernel(const int* __restrict__ deg_,
                                                   const unsigned short* __restrict__ csr16,
                                                   const float* __restrict__ als,
                                                   const float* __restrict__ ald,
                                                   const unsigned short* __restrict__ h2h,
                                                   const float* __restrict__ b2,
                                                   float* __restrict__ out) {
    int wv   = threadIdx.x >> 6;
    int lane = threadIdx.x & 63;
    int d    = blockIdx.x * 4 + wv;
    int dg   = min(deg_[d] + 1, CAP);      // +1: self-loop at slot 0
    int base = d * CAP;
    float aldd = ald[d];

    int slot = lane / 20;              // 0..2 active, 3 idle
    int idx  = lane - slot * 20;       // channel pair 0..19
    int sfirst = (int)csr16[base];
    float sm = 0.f, acc0 = 0.f, acc1 = 0.f;
    if (lane < 60) {
        #pragma unroll 2
        for (int jb = 0; jb < dg; jb += 12) {
            int ss[4]; unsigned hv[4]; float ww[4];
            #pragma unroll
            for (int i = 0; i < 4; ++i) {
                int jj = jb + slot + 3 * i;
                ss[i] = (jj < dg) ? (int)csr16[base + jj] : sfirst;
            }
            #pragma unroll
            for (int i = 0; i < 4; ++i)
                hv[i] = *(const unsigned*)(h2h + (size_t)ss[i] * 40 + 2 * idx);
            #pragma unroll
            for (int i = 0; i < 4; ++i) {
                int jj = jb + slot + 3 * i;
                float w = __expf(leaky(als[ss[i]] + aldd));
                ww[i] = (jj < dg) ? w : 0.f;
            }
            #pragma unroll
            for (int i = 0; i < 4; ++i) {
                float2 f = unp2h(hv[i]);
                acc0 += f.x * ww[i]; acc1 += f.y * ww[i]; sm += ww[i];
            }
        }
    }
    // reduce sm/acc across the 3 slots: lanes idx, idx+20, idx+40
    float s1 = __shfl(sm,   idx + 20), s2 = __shfl(sm,   idx + 40);
    float t0 = __shfl(acc0, idx + 20), t1 = __shfl(acc0, idx + 40);
    float u0 = __shfl(acc1, idx + 20), u1 = __shfl(acc1, idx + 40);
    sm += s1 + s2; acc0 += t0 + t1; acc1 += u0 + u1;
    if (lane < 20) {
        float inv = 1.f / (sm + 1e-16f);
        float2 o = make_float2(acc0 * inv + b2[2 * lane], acc1 * inv + b2[2 * lane + 1]);
        *(float2*)&out[(size_t)d * 40 + 2 * lane] = o;
    }
}

// ================= workspace layout (float-sized slots) =================
constexpr size_t OFF_H1H    = 0;          // h1 f16 (3.2M slots); h2 overlays after agg1
constexpr size_t OFF_OUT1   = 3200000;    // out1 f16 (3.2M slots)
constexpr size_t OFF_ALS1   = 6400000;    // 200,000 (als2 overlays)
constexpr size_t OFF_ALD1   = 6600000;    // 200,000 (ald2 overlays)
constexpr size_t OFF_W1T    = 6800000;    // w1t f16 [128][128] = 8192 float slots
constexpr size_t OFF_W2T    = 6808192;    // w2t f16 [40][128]  = 2560 float slots
constexpr size_t OFF_DEG    = 6860000;    // 50,000 ints
constexpr size_t OFF_CSRF   = 6920000;    // 50,000*64 u16 = 1.6M float slots
constexpr size_t WS_FLOATS  = 10120000;   // 40.5 MB

extern "C" void kernel_launch(void* const* d_in, const int* in_sizes, int n_in,
                              void* d_out, int out_size, void* d_ws, size_t ws_size,
                              hipStream_t stream) {
    const float* x   = (const float*)d_in[0];
    const int*   ei  = (const int*)  d_in[1];
    const float* W1  = (const float*)d_in[2];
    const float* as1 = (const float*)d_in[3];
    const float* ad1 = (const float*)d_in[4];
    const float* b1  = (const float*)d_in[5];
    const float* W2  = (const float*)d_in[6];
    const float* as2 = (const float*)d_in[7];
    const float* ad2 = (const float*)d_in[8];
    const float* b2  = (const float*)d_in[9];
    float* out = (float*)d_out;

    if (ws_size < WS_FLOATS * sizeof(float)) return;

    float* ws = (float*)d_ws;
    unsigned short* h1h   = (unsigned short*)(ws + OFF_H1H);
    unsigned short* h2h   = (unsigned short*)(ws + OFF_H1H);   // overlay, h1 dead after agg1
    unsigned short* out1h = (unsigned short*)(ws + OFF_OUT1);
    float* als1    = ws + OFF_ALS1;
    float* ald1    = ws + OFF_ALD1;
    float* als2    = ws + OFF_ALS1;   // overlay, dead after agg1
    float* ald2    = ws + OFF_ALD1;   // overlay
    _Float16* w1t  = (_Float16*)(ws + OFF_W1T);
    _Float16* w2t  = (_Float16*)(ws + OFF_W2T);
    int*   deg     = (int*)(ws + OFF_DEG);
    unsigned short* csr16 = (unsigned short*)(ws + OFF_CSRF);

    // ---- prep (deg=0 + W transposes), then fused [gemm1 || link->CSR sharded] ----
    prep_kernel<<<280, 256, 0, stream>>>(W1, W2, deg, w1t, w2t);
    gemm1_link_kernel<<<G1_BLOCKS + LINK_BLOCKS, 256, 0, stream>>>(
        x, w1t, as1, ad1, h1h, als1, ald1, ei, deg, csr16);

    // ---- layer 1 aggregate ----
    agg1_kernel<<<N_NODES / 4, 256, 0, stream>>>(deg, csr16, als1,
                                                 (const float4*)ald1,
                                                 h1h, b1, out1h);

    // ---- layer 2 ----
    gemm2_kernel<<<cdiv(N_NODES, 64), 256, 0, stream>>>(out1h, w2t, as2, ad2, h2h, als2, ald2);
    agg2_kernel<<<N_NODES / 4, 256, 0, stream>>>(deg, csr16, als2, ald2, h2h, b2, out);
}